// Round 4
// baseline (149.595 us; speedup 1.0000x reference)
//
#include <hip/hip_runtime.h>

// B=32, T=2048, D=64, K=4, KD=256
// out[b,t,j] = m*ha + (1-m)*(g*h_fwd + (1-g)*ha)
//   d = j % 64, m = M[b,t,d], delta = deltas[b,t,d] in {1,2,3,4} (clamped <= t+1)
//   g = exp(-relu(delta*W[j] + b[j]))
//   h_fwd = h_a[b, t-(int(delta)-1), j]  -> one of rows t, t-1, t-2, t-3
//
// d-major mapping: lane owns float4 of d across all 4 k's (16 outputs/thread).
// A wave (64 lanes) covers 4 consecutive rows (16 lanes per row):
//  - M/deltas: ONE float4 load per thread; per wave this is a single
//    contiguous 1KB region (4 rows x 256B) -- no redundant requests.
//  - candidate rows t-1..t-3 mostly lie inside the wave's own 4-row block
//    (halo = 3 rows per 4-row wave instead of 3 per row) -> 4x less
//    cross-wave cache traffic.
//  - 30 VMEM instrs/wave -> ~26KB in flight per wave (vs 9KB before).

#define TD_T 2048
#define TD_KD 256
#define TD_D 64

typedef float f32x4 __attribute__((ext_vector_type(4)));

__global__ __launch_bounds__(256) void TemporalDecay_89524298318172_kernel(
    const float* __restrict__ h_a,
    const float* __restrict__ deltas,
    const float* __restrict__ M,
    const float* __restrict__ W,
    const float* __restrict__ bias,
    float* __restrict__ out)
{
    const int lane = threadIdx.x & 63;
    const int wid  = threadIdx.x >> 6;                       // 0..3
    const int row  = blockIdx.x * 16 + wid * 4 + (lane >> 4); // b*T + t
    const int t    = row & (TD_T - 1);
    const int d0   = (lane & 15) << 2;                       // 0..60

    // M/deltas: one float4 per thread; contiguous 1KB per wave.
    const f32x4 m4  = *(const f32x4*)(M      + (size_t)row * TD_D + d0);
    const f32x4 dl4 = *(const f32x4*)(deltas + (size_t)row * TD_D + d0);

    // Candidate source rows (clamped to batch start; clamp only matters for
    // lanes where that delta value cannot be selected).
    const int rm1 = row - ((t >= 1) ? 1 : 0);
    const int rm2 = row - ((t >= 2) ? 2 : 0);
    const int rm3 = row - ((t >= 3) ? 3 : 0);

    f32x4 ha[4], c1[4], c2[4], c3[4], w4[4], b4[4];
#pragma unroll
    for (int k = 0; k < 4; ++k) {
        const int col = k * TD_D + d0;
        ha[k] = *(const f32x4*)(h_a + (size_t)row * TD_KD + col);
        c1[k] = *(const f32x4*)(h_a + (size_t)rm1 * TD_KD + col);
        c2[k] = *(const f32x4*)(h_a + (size_t)rm2 * TD_KD + col);
        c3[k] = *(const f32x4*)(h_a + (size_t)rm3 * TD_KD + col);
        w4[k] = *(const f32x4*)(W    + col);
        b4[k] = *(const f32x4*)(bias + col);
    }

#pragma unroll
    for (int k = 0; k < 4; ++k) {
        f32x4 res;
#pragma unroll
        for (int e = 0; e < 4; ++e) {
            const float delta = dl4[e];
            const float g = __expf(-fmaxf(fmaf(delta, w4[k][e], b4[k][e]), 0.0f));
            const int di = (int)delta;  // 1..4
            float hf = ha[k][e];
            hf = (di == 2) ? c1[k][e] : hf;
            hf = (di == 3) ? c2[k][e] : hf;
            hf = (di == 4) ? c3[k][e] : hf;
            const float m = m4[e];
            res[e] = m * ha[k][e] + (1.0f - m) * (g * hf + (1.0f - g) * ha[k][e]);
        }
        __builtin_nontemporal_store(
            res, (f32x4*)(out + (size_t)row * TD_KD + k * TD_D + d0));
    }
}

extern "C" void kernel_launch(void* const* d_in, const int* in_sizes, int n_in,
                              void* d_out, int out_size, void* d_ws, size_t ws_size,
                              hipStream_t stream) {
    const float* h_a    = (const float*)d_in[0];
    const float* deltas = (const float*)d_in[1];
    const float* M      = (const float*)d_in[2];
    const float* W      = (const float*)d_in[3];
    const float* bias   = (const float*)d_in[4];
    float* out          = (float*)d_out;

    // rows total = B*T = 65536; 16 rows per block (4 waves x 4 rows)
    const int rows  = in_sizes[2] / TD_D;   // M has B*T*D elements
    const int grid  = rows / 16;            // 4096 blocks
    const int block = 256;
    TemporalDecay_89524298318172_kernel<<<grid, block, 0, stream>>>(
        h_a, deltas, M, W, bias, out);
}